// Round 1
// 221.021 us; speedup vs baseline: 1.1390x; 1.1390x over previous
//
#include <hip/hip_runtime.h>
#include <cstdint>

// NNLS PGD step (all tensors FLOAT32, k int32):
//   new_X = relu(th1 @ Y + weight); Y_new = new_X + (k-1)/(k+2)*(new_X - X_old)
// out (f32) = [Y_new (KB) | new_X (KB) | k+1 (1) | weight (KB)].
// bf16 MFMA inside (absmax ~0.008 vs 0.06 threshold).
//
// R1 changes vs baseline (105.8 us/dispatch):
//  - LDS double-buffer in the K-loop: ONE barrier per K-step (was 2).
//    Prefetch issued AFTER the barrier so the vmcnt(0) drain at
//    __syncthreads never hits in-flight loads.
//  - Epilogue remap: lane -> (row = t*4 + lane>>4, col = (lane&15)*4) so
//    every global load/store instruction covers 4x 256B contiguous runs
//    (was 64x scattered 16B chunks at 64B stride).
//  - Epilogue LDS tile is wave-private ([16][68] pad): no intra-epilogue
//    barriers (same-wave DS ops are in-order); single post-loop barrier.

#define KDIM 1024
#define NDIM 8192
#define KB_ELEMS (1024UL * 8192UL)
#define LDA 40  // LDS row stride in ushorts (80B = 20 dwords -> bank-spread rows)

typedef short short8 __attribute__((ext_vector_type(8)));
typedef float f32x4 __attribute__((ext_vector_type(4)));

struct __attribute__((aligned(4))) f4u { float x, y, z, w; };  // 4B-aligned 16B store

__device__ __forceinline__ uint32_t pk2(float a, float b) {
  uint32_t ua = __builtin_bit_cast(uint32_t, a) + 0x8000u;
  uint32_t ub = __builtin_bit_cast(uint32_t, b) + 0x8000u;
  return (ua >> 16) | (ub & 0xFFFF0000u);
}

// 128x128 tile, BK=32, 512 threads = 8 waves (4m x 2n), wave tile 32x64 (2x4 MFMA).
__global__ __launch_bounds__(512, 4) void nnls_gemm(
    const float* __restrict__ th1, const float* __restrict__ Y,
    const float* __restrict__ xold, const int* __restrict__ kin,
    const float* __restrict__ weight, float* __restrict__ out)
{
  __shared__ __align__(16) char smem[40960];
  // double-buffered staging: buf p at {As, Bs} offsets p*20480
  unsigned short* As0 = (unsigned short*)smem;              // 128*40*2 = 10240 B
  unsigned short* Bs0 = (unsigned short*)(smem + 10240);
  unsigned short* As1 = (unsigned short*)(smem + 20480);
  unsigned short* Bs1 = (unsigned short*)(smem + 30720);

  const int tid  = threadIdx.x;
  const int lane = tid & 63;
  const int w    = tid >> 6;            // 0..7
  const int wm = w >> 1, wn = w & 1;    // 4 x 2 wave grid
  const int quad = lane >> 4, nl = lane & 15;

  const int m0 = blockIdx.y * 128;
  const int n0 = blockIdx.x * 128;

  // A staging: thread -> rows {ar, ar+64}, cols ac*4 (float4); 128B runs per instr
  const int ar = tid >> 3;              // 0..63
  const int ac = tid & 7;
  const float* abase = th1 + (size_t)(m0 + ar) * KDIM + ac * 4;

  // B staging: thread -> row n=bn (tile col), k = bk..bk+7 (8 scalar loads)
  const int bn = tid & 127;
  const int bk = (tid >> 7) * 8;        // 0,8,16,24 (wave-uniform pairs)
  const float* ybase = Y + (size_t)bk * NDIM + n0 + bn;

  float4 ab[2];
  float  yb[8];
  ab[0] = *(const float4*)(abase);
  ab[1] = *(const float4*)(abase + (size_t)64 * KDIM);
#pragma unroll
  for (int r = 0; r < 8; ++r) yb[r] = ybase[(size_t)r * NDIM];

  f32x4 acc[2][4] = {};

#pragma unroll 2
  for (int kt = 0; kt < 32; ++kt) {
    unsigned short* Asp = (kt & 1) ? As1 : As0;
    unsigned short* Bsp = (kt & 1) ? Bs1 : Bs0;

    // ---- convert + stage into buf[kt&1] (conflict-free with LDA=40) ----
    {
      uint2 d0; d0.x = pk2(ab[0].x, ab[0].y); d0.y = pk2(ab[0].z, ab[0].w);
      *(uint2*)&Asp[ar * LDA + ac * 4] = d0;
      uint2 d1; d1.x = pk2(ab[1].x, ab[1].y); d1.y = pk2(ab[1].z, ab[1].w);
      *(uint2*)&Asp[(ar + 64) * LDA + ac * 4] = d1;
      uint4 e;
      e.x = pk2(yb[0], yb[1]); e.y = pk2(yb[2], yb[3]);
      e.z = pk2(yb[4], yb[5]); e.w = pk2(yb[6], yb[7]);
      *(uint4*)&Bsp[bn * LDA + bk] = e;  // single ds_write_b128
    }
    __syncthreads();  // the ONLY barrier per K-step (vmcnt already drained here)

    // prefetch tile kt+1 into regs; issued after barrier so the loads stay
    // in flight under the frag reads + MFMAs, waited at next iter's convert
    if (kt < 31) {
      const float* an = abase + (kt + 1) * 32;
      ab[0] = *(const float4*)(an);
      ab[1] = *(const float4*)(an + (size_t)64 * KDIM);
      const float* yn = ybase + (size_t)((kt + 1) * 32) * NDIM;
#pragma unroll
      for (int r = 0; r < 8; ++r) yb[r] = yn[(size_t)r * NDIM];
    }

    short8 af[2], bf[4];
#pragma unroll
    for (int i = 0; i < 2; ++i)
      af[i] = *(const short8*)&Asp[(wm * 32 + i * 16 + nl) * LDA + quad * 8];
#pragma unroll
    for (int j = 0; j < 4; ++j)
      bf[j] = *(const short8*)&Bsp[(wn * 64 + j * 16 + nl) * LDA + quad * 8];
#pragma unroll
    for (int i = 0; i < 2; ++i)
#pragma unroll
      for (int j = 0; j < 4; ++j)
        acc[i][j] = __builtin_amdgcn_mfma_f32_16x16x32_bf16(af[i], bf[j], acc[i][j], 0, 0, 0);
    // no second barrier: next iter writes the OTHER buffer; writes to THIS
    // buffer are 2 barriers away (iter kt+2 stages after barrier kt+1)
  }
  __syncthreads();  // protect As/Bs before epilogue reuses smem

  // ---- epilogue: wave-private LDS transpose -> contiguous float4 I/O ----
  const float kf  = (float)kin[0];
  const float mom = (kf - 1.0f) / (kf + 2.0f);
  float* ep = (float*)smem + w * 1088;  // 16 rows x 68 f32 (pad) = 4352B per wave
  const int u  = lane >> 4;             // read row-in-group 0..3
  const int mc = lane & 15;             // read col group (x4 floats)

#pragma unroll
  for (int i = 0; i < 2; ++i) {
    // scatter acc chunk i (16 rows x 64 cols); pad-68 rows -> 2-way writes (free)
#pragma unroll
    for (int j = 0; j < 4; ++j)
#pragma unroll
      for (int r = 0; r < 4; ++r)
        ep[(quad * 4 + r) * 68 + (j * 16 + nl)] = acc[i][j][r];
    // no barrier: ep is wave-private; same-wave DS ops are in-order

    const int mgb = m0 + wm * 32 + i * 16;
#pragma unroll
    for (int t = 0; t < 4; ++t) {
      const int row = t * 4 + u;
      const float4 cv = *(const float4*)&ep[row * 68 + mc * 4];  // b128, floor-balanced
      const int ng = n0 + wn * 64 + mc * 4;
      const size_t idx = (size_t)(mgb + row) * NDIM + ng;        // 4 rows x 256B runs
      const float4 wv = *(const float4*)&weight[idx];
      const float4 xo = *(const float4*)&xold[idx];
      float4 nx, yn;
      nx.x = fmaxf(cv.x + wv.x, 0.0f); nx.y = fmaxf(cv.y + wv.y, 0.0f);
      nx.z = fmaxf(cv.z + wv.z, 0.0f); nx.w = fmaxf(cv.w + wv.w, 0.0f);
      yn.x = nx.x + mom * (nx.x - xo.x); yn.y = nx.y + mom * (nx.y - xo.y);
      yn.z = nx.z + mom * (nx.z - xo.z); yn.w = nx.w + mom * (nx.w - xo.w);
      *(float4*)&out[idx] = yn;               // Y_new (16B aligned)
      *(float4*)&out[KB_ELEMS + idx] = nx;    // new_X (16B aligned)
      f4u s; s.x = wv.x; s.y = wv.y; s.z = wv.z; s.w = wv.w;
      *(f4u*)&out[2 * KB_ELEMS + 1 + idx] = s;  // weight passthrough (4B aligned)
    }
    // no barrier: i=1 scatter is same-wave WAR on ep, DS pipe is in-order
  }

  if (blockIdx.x == 0 && blockIdx.y == 0 && tid == 0)
    out[2 * KB_ELEMS] = (float)(kin[0] + 1);
}

extern "C" void kernel_launch(void* const* d_in, const int* in_sizes, int n_in,
                              void* d_out, int out_size, void* d_ws, size_t ws_size,
                              hipStream_t stream) {
  const float* th1  = (const float*)d_in[0];
  const float* Y    = (const float*)d_in[1];
  const float* xold = (const float*)d_in[2];
  const int*   kin  = (const int*)d_in[3];
  const float* wgt  = (const float*)d_in[4];
  float* out = (float*)d_out;

  dim3 grid(NDIM / 128, KDIM / 128);  // 64 x 8 = 512 blocks, 2/CU, 16 waves/CU
  nnls_gemm<<<grid, 512, 0, stream>>>(th1, Y, xold, kin, wgt, out);
}